// Round 12
// baseline (752.583 us; speedup 1.0000x reference)
//
#include <hip/hip_runtime.h>
#include <stdint.h>

#define HH 4096
#define WW 4096
#define NPIX (HH * WW)
#define NBINS 8192
#define NFRAG 64
#define FRAG_PIX (512 * 512)   // 2^18
#define WPR 64                 // u64 words per row (4096/64)
#define NWORDS (HH * WPR)      // 262144
#define CAP 4096               // per-fragment critical-band capacity

// Reference stop conditions (integer-exact):
//   phase0 stop: cnt >= 31458 <=> th < V_HI,  V_HI = v_sorted[230686]
//   phase1 stop: cnt <= 20971 <=> th >= V_LO, V_LO = v_sorted[241172]
#define RANK_HI 230686u
#define RANK_LO 241172u

typedef unsigned long long u64;

__device__ __forceinline__ int frag_of(int py, int px) {
  return ((py >> 9) << 3) + (px >> 9);
}

__device__ __forceinline__ int bin_of(float v) {
  int b = (int)(v * 8192.0f);   // monotone f32 map
  if (b < 0) b = 0;
  if (b > NBINS - 1) b = NBINS - 1;
  return b;
}

// ---------------------------------------------------------------------------
// VERIFIED bit-exact blur arithmetic (numpy pairwise_sum n=25 tree over
// materialized (windows*k), row-major taps, OOB -> exact 0). DO NOT TOUCH.
// ---------------------------------------------------------------------------
__device__ __forceinline__ float blur_px(const float* __restrict__ x, int py, int px) {
  const float K = (float)(1.0 / 25.0);
  float p[25];
#pragma unroll
  for (int i = 0; i < 25; ++i) {
    int dy = i / 5 - 2;
    int dx = i % 5 - 2;
    int yy = py + dy;
    int xx = px + dx;
    float v = 0.0f;
    if ((unsigned)yy < (unsigned)HH && (unsigned)xx < (unsigned)WW) {
      v = x[yy * WW + xx];
    }
    p[i] = __fmul_rn(v, K);
  }
  float r0 = __fadd_rn(__fadd_rn(p[0], p[8]),  p[16]);
  float r1 = __fadd_rn(__fadd_rn(p[1], p[9]),  p[17]);
  float r2 = __fadd_rn(__fadd_rn(p[2], p[10]), p[18]);
  float r3 = __fadd_rn(__fadd_rn(p[3], p[11]), p[19]);
  float r4 = __fadd_rn(__fadd_rn(p[4], p[12]), p[20]);
  float r5 = __fadd_rn(__fadd_rn(p[5], p[13]), p[21]);
  float r6 = __fadd_rn(__fadd_rn(p[6], p[14]), p[22]);
  float r7 = __fadd_rn(__fadd_rn(p[7], p[15]), p[23]);
  float res = __fadd_rn(
      __fadd_rn(__fadd_rn(r0, r1), __fadd_rn(r2, r3)),
      __fadd_rn(__fadd_rn(r4, r5), __fadd_rn(r6, r7)));
  return __fadd_rn(res, p[24]);
}

// ---------------------------------------------------------------------------
// 1) FUSED blur + per-fragment LDS histogram.
//    1024 blocks: block b -> fragment f=b>>4, strip s=b&15 (32 rows x 512 cols).
// ---------------------------------------------------------------------------
__global__ void blur_hist_kernel(const float* __restrict__ x,
                                 float* __restrict__ out,
                                 uint32_t* __restrict__ hist) {
  __shared__ uint32_t lh[NBINS];
  int tid = threadIdx.x;
  for (int i = tid; i < NBINS; i += 256) lh[i] = 0;
  __syncthreads();
  int f = blockIdx.x >> 4;
  int s = blockIdx.x & 15;
  int row0 = (f >> 3) * 512 + s * 32;
  int col0 = (f & 7) * 512;
  // 32 rows x 128 float4s = 4096 float4 units
  for (int it = tid; it < 32 * 128; it += 256) {
    int rr = it >> 7;
    int c4 = it & 127;
    int py = row0 + rr;
    int px = col0 + c4 * 4;
    float4 res;
    res.x = blur_px(x, py, px + 0);
    res.y = blur_px(x, py, px + 1);
    res.z = blur_px(x, py, px + 2);
    res.w = blur_px(x, py, px + 3);
    *(float4*)(out + (size_t)py * WW + px) = res;
    atomicAdd(&lh[bin_of(res.x)], 1u);
    atomicAdd(&lh[bin_of(res.y)], 1u);
    atomicAdd(&lh[bin_of(res.z)], 1u);
    atomicAdd(&lh[bin_of(res.w)], 1u);
  }
  __syncthreads();
  uint32_t* hf = hist + f * NBINS;
  for (int i = tid; i < NBINS; i += 256) {
    uint32_t c = lh[i];
    if (c) atomicAdd(&hf[i], c);
  }
}

// ---------------------------------------------------------------------------
// 2) find critical buckets + local ranks (no P array materialized).
//    bins4[f] = (bhi, blo, khi, klo).
// ---------------------------------------------------------------------------
__global__ void findcrit_kernel(const uint32_t* __restrict__ hist,
                                int4* __restrict__ bins4) {
  __shared__ uint32_t segsum[256];
  __shared__ uint32_t segoff[256];
  __shared__ int4 result;
  int f = blockIdx.x;
  int tid = threadIdx.x;
  const uint32_t* hf = hist + f * NBINS;
  int base = tid * 32;
  uint32_t h32[32];
  uint32_t s = 0;
  for (int i = 0; i < 32; ++i) { h32[i] = hf[base + i]; s += h32[i]; }
  segsum[tid] = s;
  __syncthreads();
  if (tid == 0) {
    uint32_t a = 0;
    for (int i = 0; i < 256; ++i) { segoff[i] = a; a += segsum[i]; }
  }
  __syncthreads();
  uint32_t st = segoff[tid];
  uint32_t en = st + segsum[tid];
  if (st <= RANK_HI && RANK_HI < en) {
    uint32_t a = st;
    for (int i = 0; i < 32; ++i) {
      uint32_t nx = a + h32[i];
      if (RANK_HI < nx) { result.x = base + i; result.z = (int)(RANK_HI - a); break; }
      a = nx;
    }
  }
  if (st <= RANK_LO && RANK_LO < en) {
    uint32_t a = st;
    for (int i = 0; i < 32; ++i) {
      uint32_t nx = a + h32[i];
      if (RANK_LO < nx) { result.y = base + i; result.w = (int)(RANK_LO - a); break; }
      a = nx;
    }
  }
  __syncthreads();
  if (tid == 0) bins4[f] = result;
}

// ---------------------------------------------------------------------------
// 3) gather critical-bucket values
// ---------------------------------------------------------------------------
__global__ void gather_kernel(const float* __restrict__ blur,
                              const int4* __restrict__ bins4,
                              float* __restrict__ band,
                              uint32_t* __restrict__ bandcnt) {
  int idx = blockIdx.x * blockDim.x + threadIdx.x;
  float v = blur[idx];
  int f = frag_of(idx >> 12, idx & (WW - 1));
  int4 info = bins4[f];
  int b = bin_of(v);
  if (b == info.x || b == info.y) {
    uint32_t pos = atomicAdd(&bandcnt[f], 1u);
    if (pos < CAP) band[(size_t)f * CAP + pos] = v;
  }
}

// ---------------------------------------------------------------------------
// 4) exact order-statistic selection within the critical buckets
// ---------------------------------------------------------------------------
__global__ void select_kernel(const float* __restrict__ band,
                              const uint32_t* __restrict__ bandcnt,
                              const int4* __restrict__ bins4,
                              float2* __restrict__ vhl) {
  __shared__ float wv[CAP];
  __shared__ float res[2];
  int f = blockIdx.x;
  int tid = threadIdx.x;
  int n = (int)bandcnt[f];
  if (n > CAP) n = CAP;
  for (int i = tid; i < n; i += 256) wv[i] = band[(size_t)f * CAP + i];
  __syncthreads();
  int4 info = bins4[f];
#pragma unroll
  for (int sel = 0; sel < 2; ++sel) {
    int tb = sel ? info.y : info.x;
    int k  = sel ? info.w : info.z;
    for (int i = tid; i < n; i += 256) {
      float w = wv[i];
      if (bin_of(w) != tb) continue;
      int less = 0, leq = 0;
      for (int j = 0; j < n; ++j) {
        float u = wv[j];
        if (bin_of(u) == tb) {
          less += (u < w) ? 1 : 0;
          leq  += (u <= w) ? 1 : 0;
        }
      }
      if (less <= k && k < leq) res[sel] = w;   // unique value; benign race
    }
  }
  __syncthreads();
  if (tid == 0) vhl[f] = make_float2(res[0], res[1]);
}

// ---------------------------------------------------------------------------
// 5) threshold walk — the reference's scalar while-loops, all 64 lanes
//    redundantly computing the same uniform walk (no divergence).
//    while(cnt<31458): th-=step  <=>  while(th>=VH): th-=step
//    while(cnt>20971): th+=step  <=>  while(th<VL):  th+=step
// ---------------------------------------------------------------------------
__global__ void walk_kernel(const float2* __restrict__ vhl, float* __restrict__ th_out) {
  int lane = threadIdx.x;
  float2 mine = vhl[lane];   // lane f holds fragment f's (V_HI, V_LO)
  float th = 0.5f;           // TH1_INIT
  for (int f = 0; f < NFRAG; ++f) {
    float VH = __shfl(mine.x, f);
    float VL = __shfl(mine.y, f);
    while (th >= VH) th = __fadd_rn(th, -0.0005f);
    while (th <  VL) th = __fadd_rn(th,  0.0005f);
    if (lane == 0) th_out[f] = th;
  }
}

// ---------------------------------------------------------------------------
// 6) mask + bit-pack via wave ballot
// ---------------------------------------------------------------------------
__global__ void mask_pack_kernel(const float* __restrict__ blur,
                                 const float* __restrict__ th,
                                 u64* __restrict__ pk) {
  int idx = blockIdx.x * blockDim.x + threadIdx.x;
  int px = idx & (WW - 1);
  int py = idx >> 12;
  bool on = blur[idx] > th[frag_of(py, px)];
  u64 w = __ballot(on);
  if ((threadIdx.x & 63) == 0) pk[idx >> 6] = w;
}

// ---------------------------------------------------------------------------
// 7) fused dilate (H+V) on packed bits; OOB = 0 (clipped window).
//    256 blocks: tile 64 rows x 16 wordcols.
// ---------------------------------------------------------------------------
__global__ void dilate_kernel(const u64* __restrict__ in, u64* __restrict__ out) {
  __shared__ u64 hm[68][16];
  int bx = blockIdx.x & 3;
  int by = blockIdx.x >> 2;
  int r0 = by * 64, c0 = bx * 16;
  int tid = threadIdx.x;
  for (int it = tid; it < 68 * 16; it += 256) {
    int rr = it >> 4;
    int cc = it & 15;
    int gy = r0 - 2 + rr;
    int gx = c0 + cc;
    u64 m = 0, l = 0, r = 0;
    if ((unsigned)gy < (unsigned)HH) {
      m = in[gy * WPR + gx];
      l = (gx > 0) ? in[gy * WPR + gx - 1] : 0ull;
      r = (gx < WPR - 1) ? in[gy * WPR + gx + 1] : 0ull;
    }
    hm[rr][cc] = m | (m << 1) | (m << 2) | (m >> 1) | (m >> 2)
                   | (l >> 62) | (l >> 63) | (r << 62) | (r << 63);
  }
  __syncthreads();
  for (int it = tid; it < 64 * 16; it += 256) {
    int rr = it >> 4;
    int cc = it & 15;
    u64 v = hm[rr][cc] | hm[rr + 1][cc] | hm[rr + 2][cc] | hm[rr + 3][cc] | hm[rr + 4][cc];
    out[(r0 + rr) * WPR + c0 + cc] = v;
  }
}

// ---------------------------------------------------------------------------
// 8) fused erode (De Morgan: dilate of complement) + unpack to f32.
//    out = 1 - bit(dilate(~d1))  == erode(d1).
// ---------------------------------------------------------------------------
__global__ void erode_unpack_kernel(const u64* __restrict__ in, float* __restrict__ out) {
  __shared__ u64 hm[68][16];
  __shared__ u64 d2[64][16];
  int bx = blockIdx.x & 3;
  int by = blockIdx.x >> 2;
  int r0 = by * 64, c0 = bx * 16;
  int tid = threadIdx.x;
  for (int it = tid; it < 68 * 16; it += 256) {
    int rr = it >> 4;
    int cc = it & 15;
    int gy = r0 - 2 + rr;
    int gx = c0 + cc;
    u64 m = 0, l = 0, r = 0;
    if ((unsigned)gy < (unsigned)HH) {
      m = ~in[gy * WPR + gx];
      l = (gx > 0) ? ~in[gy * WPR + gx - 1] : 0ull;
      r = (gx < WPR - 1) ? ~in[gy * WPR + gx + 1] : 0ull;
    }
    hm[rr][cc] = m | (m << 1) | (m << 2) | (m >> 1) | (m >> 2)
                   | (l >> 62) | (l >> 63) | (r << 62) | (r << 63);
  }
  __syncthreads();
  for (int it = tid; it < 64 * 16; it += 256) {
    int rr = it >> 4;
    int cc = it & 15;
    d2[rr][cc] = hm[rr][cc] | hm[rr + 1][cc] | hm[rr + 2][cc] | hm[rr + 3][cc] | hm[rr + 4][cc];
  }
  __syncthreads();
  // unpack: 64 rows x 1024 px -> 16384 float4s, coalesced
  int colbase = c0 * 64;
  for (int it = tid; it < 64 * 256; it += 256) {
    int rr = it >> 8;
    int px0 = (it & 255) * 4;
    u64 w = d2[rr][px0 >> 6];
    int sh = px0 & 63;
    float4 o;
    o.x = (float)(1 - (int)((w >> (sh + 0)) & 1ull));
    o.y = (float)(1 - (int)((w >> (sh + 1)) & 1ull));
    o.z = (float)(1 - (int)((w >> (sh + 2)) & 1ull));
    o.w = (float)(1 - (int)((w >> (sh + 3)) & 1ull));
    *(float4*)(out + (size_t)(r0 + rr) * WW + colbase + px0) = o;
  }
}

// ---------------------------------------------------------------------------
extern "C" void kernel_launch(void* const* d_in, const int* in_sizes, int n_in,
                              void* d_out, int out_size, void* d_ws, size_t ws_size,
                              hipStream_t stream) {
  const float* x = (const float*)d_in[0];
  if (n_in > 1 && in_sizes[0] != NPIX) x = (const float*)d_in[1];
  float* out = (float*)d_out;
  char* ws = (char*)d_ws;

  // workspace layout — TOTAL ~7.4 MB
  const size_t OFF_HIST = 0;          // 2,097,152
  const size_t OFF_TH   = 2097152;    // 256
  const size_t OFF_PKA  = 2097408;    // 2,097,152
  const size_t OFF_PKB  = 4194560;    // 2,097,152
  const size_t OFF_BCNT = 6291712;    // 256
  const size_t OFF_BINS = 6291968;    // 1,024
  const size_t OFF_VHL  = 6292992;    // 512
  const size_t OFF_BAND = 6293504;    // 1,048,576 (end ~7.34 MB)
  uint32_t* hist    = (uint32_t*)(ws + OFF_HIST);
  float*    th      = (float*)(ws + OFF_TH);
  u64*      PKA     = (u64*)(ws + OFF_PKA);
  u64*      PKB     = (u64*)(ws + OFF_PKB);
  uint32_t* bandcnt = (uint32_t*)(ws + OFF_BCNT);
  int4*     bins4   = (int4*)(ws + OFF_BINS);
  float2*   vhl     = (float2*)(ws + OFF_VHL);
  float*    band    = (float*)(ws + OFF_BAND);

  float* blurred = out;   // blur lives in d_out; erode_unpack rewrites it

  const int TPB = 256;
  const int NB = NPIX / TPB;   // 65536

  hipMemsetAsync(hist, 0, (size_t)NFRAG * NBINS * sizeof(uint32_t), stream);
  hipMemsetAsync(bandcnt, 0, NFRAG * sizeof(uint32_t), stream);
  blur_hist_kernel<<<1024, TPB, 0, stream>>>(x, blurred, hist);
  findcrit_kernel<<<NFRAG, TPB, 0, stream>>>(hist, bins4);
  gather_kernel<<<NB, TPB, 0, stream>>>(blurred, bins4, band, bandcnt);
  select_kernel<<<NFRAG, TPB, 0, stream>>>(band, bandcnt, bins4, vhl);
  walk_kernel<<<1, 64, 0, stream>>>(vhl, th);
  mask_pack_kernel<<<NB, TPB, 0, stream>>>(blurred, th, PKA);
  dilate_kernel<<<256, TPB, 0, stream>>>(PKA, PKB);
  erode_unpack_kernel<<<256, TPB, 0, stream>>>(PKB, out);
}

// Round 13
// 478.107 us; speedup vs baseline: 1.5741x; 1.5741x over previous
//
#include <hip/hip_runtime.h>
#include <stdint.h>

#define HH 4096
#define WW 4096
#define NPIX (HH * WW)
#define NBINS 8192
#define NFRAG 64
#define FRAG_PIX (512 * 512)   // 2^18
#define WPR 64                 // u64 words per row (4096/64)
#define NWORDS (HH * WPR)      // 262144
#define CAP 4096               // per-fragment critical-band capacity

// Reference stop conditions (integer-exact):
//   phase0 stop: cnt >= 31458 <=> th < V_HI,  V_HI = v_sorted[230686]
//   phase1 stop: cnt <= 20971 <=> th >= V_LO, V_LO = v_sorted[241172]
#define RANK_HI 230686u
#define RANK_LO 241172u

typedef unsigned long long u64;

__device__ __forceinline__ int frag_of(int py, int px) {
  return ((py >> 9) << 3) + (px >> 9);
}

__device__ __forceinline__ int bin_of(float v) {
  int b = (int)(v * 8192.0f);   // monotone f32 map
  if (b < 0) b = 0;
  if (b > NBINS - 1) b = NBINS - 1;
  return b;
}

// ---------------------------------------------------------------------------
// VERIFIED bit-exact blur tree (numpy pairwise_sum n=25 over materialized
// (windows*k), row-major taps, OOB -> exact 0). rowbuf[r][j] = x[py-2+r][px-2+j].
// DO NOT TOUCH THE ARITHMETIC ORDER.
// ---------------------------------------------------------------------------
__device__ __forceinline__ float blur_tree(const float rowbuf[5][8], int e) {
  const float K = (float)(1.0 / 25.0);
  float p[25];
#pragma unroll
  for (int i = 0; i < 25; ++i) {
    p[i] = __fmul_rn(rowbuf[i / 5][e + (i % 5)], K);
  }
  float r0 = __fadd_rn(__fadd_rn(p[0], p[8]),  p[16]);
  float r1 = __fadd_rn(__fadd_rn(p[1], p[9]),  p[17]);
  float r2 = __fadd_rn(__fadd_rn(p[2], p[10]), p[18]);
  float r3 = __fadd_rn(__fadd_rn(p[3], p[11]), p[19]);
  float r4 = __fadd_rn(__fadd_rn(p[4], p[12]), p[20]);
  float r5 = __fadd_rn(__fadd_rn(p[5], p[13]), p[21]);
  float r6 = __fadd_rn(__fadd_rn(p[6], p[14]), p[22]);
  float r7 = __fadd_rn(__fadd_rn(p[7], p[15]), p[23]);
  float res = __fadd_rn(
      __fadd_rn(__fadd_rn(r0, r1), __fadd_rn(r2, r3)),
      __fadd_rn(__fadd_rn(r4, r5), __fadd_rn(r6, r7)));
  return __fadd_rn(res, p[24]);
}

// ---------------------------------------------------------------------------
// 1) FUSED blur + per-fragment LDS histogram, vector-loaded.
//    1024 blocks: fragment f=b>>4, strip s=b&15 (32 rows x 512 cols).
//    Each thread-iteration: 4 consecutive px; 5 rows loaded as f2+f4+f2
//    (15 vector loads vs 100 scalar).
// ---------------------------------------------------------------------------
__global__ void blur_hist_kernel(const float* __restrict__ x,
                                 float* __restrict__ out,
                                 uint32_t* __restrict__ hist) {
  __shared__ uint32_t lh[NBINS];
  int tid = threadIdx.x;
  for (int i = tid; i < NBINS; i += 256) lh[i] = 0;
  __syncthreads();
  int f = blockIdx.x >> 4;
  int s = blockIdx.x & 15;
  int row0 = (f >> 3) * 512 + s * 32;
  int col0 = (f & 7) * 512;
  for (int it = tid; it < 32 * 128; it += 256) {
    int rr = it >> 7;
    int c4 = it & 127;
    int py = row0 + rr;
    int px = col0 + c4 * 4;
    float rowbuf[5][8];
    bool interior = (px >= 2) && (px + 5 < WW);
#pragma unroll
    for (int r = 0; r < 5; ++r) {
      int yy = py - 2 + r;
      if ((unsigned)yy >= (unsigned)HH) {
#pragma unroll
        for (int j = 0; j < 8; ++j) rowbuf[r][j] = 0.0f;
      } else if (interior) {
        const float* rp = x + (size_t)yy * WW + px;
        float2 L = *(const float2*)(rp - 2);
        float4 M = *(const float4*)(rp);
        float2 R = *(const float2*)(rp + 4);
        rowbuf[r][0] = L.x; rowbuf[r][1] = L.y;
        rowbuf[r][2] = M.x; rowbuf[r][3] = M.y;
        rowbuf[r][4] = M.z; rowbuf[r][5] = M.w;
        rowbuf[r][6] = R.x; rowbuf[r][7] = R.y;
      } else {
#pragma unroll
        for (int j = 0; j < 8; ++j) {
          int xx = px - 2 + j;
          rowbuf[r][j] = ((unsigned)xx < (unsigned)WW) ? x[(size_t)yy * WW + xx] : 0.0f;
        }
      }
    }
    float4 res;
    res.x = blur_tree(rowbuf, 0);
    res.y = blur_tree(rowbuf, 1);
    res.z = blur_tree(rowbuf, 2);
    res.w = blur_tree(rowbuf, 3);
    *(float4*)(out + (size_t)py * WW + px) = res;
    atomicAdd(&lh[bin_of(res.x)], 1u);
    atomicAdd(&lh[bin_of(res.y)], 1u);
    atomicAdd(&lh[bin_of(res.z)], 1u);
    atomicAdd(&lh[bin_of(res.w)], 1u);
  }
  __syncthreads();
  uint32_t* hf = hist + f * NBINS;
  for (int i = tid; i < NBINS; i += 256) {
    uint32_t c = lh[i];
    if (c) atomicAdd(&hf[i], c);
  }
}

// ---------------------------------------------------------------------------
// 2) find critical buckets + local ranks. bins4[f] = (bhi, blo, khi, klo).
// ---------------------------------------------------------------------------
__global__ void findcrit_kernel(const uint32_t* __restrict__ hist,
                                int4* __restrict__ bins4) {
  __shared__ uint32_t segsum[256];
  __shared__ uint32_t segoff[256];
  __shared__ int4 result;
  int f = blockIdx.x;
  int tid = threadIdx.x;
  const uint32_t* hf = hist + f * NBINS;
  int base = tid * 32;
  uint32_t h32[32];
  uint32_t s = 0;
  for (int i = 0; i < 32; ++i) { h32[i] = hf[base + i]; s += h32[i]; }
  segsum[tid] = s;
  __syncthreads();
  if (tid == 0) {
    uint32_t a = 0;
    for (int i = 0; i < 256; ++i) { segoff[i] = a; a += segsum[i]; }
  }
  __syncthreads();
  uint32_t st = segoff[tid];
  uint32_t en = st + segsum[tid];
  if (st <= RANK_HI && RANK_HI < en) {
    uint32_t a = st;
    for (int i = 0; i < 32; ++i) {
      uint32_t nx = a + h32[i];
      if (RANK_HI < nx) { result.x = base + i; result.z = (int)(RANK_HI - a); break; }
      a = nx;
    }
  }
  if (st <= RANK_LO && RANK_LO < en) {
    uint32_t a = st;
    for (int i = 0; i < 32; ++i) {
      uint32_t nx = a + h32[i];
      if (RANK_LO < nx) { result.y = base + i; result.w = (int)(RANK_LO - a); break; }
      a = nx;
    }
  }
  __syncthreads();
  if (tid == 0) bins4[f] = result;
}

// ---------------------------------------------------------------------------
// 3) gather critical-bucket values
// ---------------------------------------------------------------------------
__global__ void gather_kernel(const float* __restrict__ blur,
                              const int4* __restrict__ bins4,
                              float* __restrict__ band,
                              uint32_t* __restrict__ bandcnt) {
  int idx = blockIdx.x * blockDim.x + threadIdx.x;
  float v = blur[idx];
  int f = frag_of(idx >> 12, idx & (WW - 1));
  int4 info = bins4[f];
  int b = bin_of(v);
  if (b == info.x || b == info.y) {
    uint32_t pos = atomicAdd(&bandcnt[f], 1u);
    if (pos < CAP) band[(size_t)f * CAP + pos] = v;
  }
}

// ---------------------------------------------------------------------------
// 4) exact order-statistic selection within the critical buckets
// ---------------------------------------------------------------------------
__global__ void select_kernel(const float* __restrict__ band,
                              const uint32_t* __restrict__ bandcnt,
                              const int4* __restrict__ bins4,
                              float2* __restrict__ vhl) {
  __shared__ float wv[CAP];
  __shared__ float res[2];
  int f = blockIdx.x;
  int tid = threadIdx.x;
  int n = (int)bandcnt[f];
  if (n > CAP) n = CAP;
  for (int i = tid; i < n; i += 256) wv[i] = band[(size_t)f * CAP + i];
  __syncthreads();
  int4 info = bins4[f];
#pragma unroll
  for (int sel = 0; sel < 2; ++sel) {
    int tb = sel ? info.y : info.x;
    int k  = sel ? info.w : info.z;
    for (int i = tid; i < n; i += 256) {
      float w = wv[i];
      if (bin_of(w) != tb) continue;
      int less = 0, leq = 0;
      for (int j = 0; j < n; ++j) {
        float u = wv[j];
        if (bin_of(u) == tb) {
          less += (u < w) ? 1 : 0;
          leq  += (u <= w) ? 1 : 0;
        }
      }
      if (less <= k && k < leq) res[sel] = w;   // unique value; benign race
    }
  }
  __syncthreads();
  if (tid == 0) vhl[f] = make_float2(res[0], res[1]);
}

// ---------------------------------------------------------------------------
// 5) threshold walk — reference's scalar while-loops (uniform, one wave)
// ---------------------------------------------------------------------------
__global__ void walk_kernel(const float2* __restrict__ vhl, float* __restrict__ th_out) {
  int lane = threadIdx.x;
  float2 mine = vhl[lane];   // lane f holds fragment f's (V_HI, V_LO)
  float th = 0.5f;           // TH1_INIT
  for (int f = 0; f < NFRAG; ++f) {
    float VH = __shfl(mine.x, f);
    float VL = __shfl(mine.y, f);
    while (th >= VH) th = __fadd_rn(th, -0.0005f);
    while (th <  VL) th = __fadd_rn(th,  0.0005f);
    if (lane == 0) th_out[f] = th;
  }
}

// ---------------------------------------------------------------------------
// 6) mask + bit-pack via wave ballot
// ---------------------------------------------------------------------------
__global__ void mask_pack_kernel(const float* __restrict__ blur,
                                 const float* __restrict__ th,
                                 u64* __restrict__ pk) {
  int idx = blockIdx.x * blockDim.x + threadIdx.x;
  int px = idx & (WW - 1);
  int py = idx >> 12;
  bool on = blur[idx] > th[frag_of(py, px)];
  u64 w = __ballot(on);
  if ((threadIdx.x & 63) == 0) pk[idx >> 6] = w;
}

// ---------------------------------------------------------------------------
// 7) fused dilate (H+V) on packed bits; OOB = 0 (clipped window).
// ---------------------------------------------------------------------------
__global__ void dilate_kernel(const u64* __restrict__ in, u64* __restrict__ out) {
  __shared__ u64 hm[68][16];
  int bx = blockIdx.x & 3;
  int by = blockIdx.x >> 2;
  int r0 = by * 64, c0 = bx * 16;
  int tid = threadIdx.x;
  for (int it = tid; it < 68 * 16; it += 256) {
    int rr = it >> 4;
    int cc = it & 15;
    int gy = r0 - 2 + rr;
    int gx = c0 + cc;
    u64 m = 0, l = 0, r = 0;
    if ((unsigned)gy < (unsigned)HH) {
      m = in[gy * WPR + gx];
      l = (gx > 0) ? in[gy * WPR + gx - 1] : 0ull;
      r = (gx < WPR - 1) ? in[gy * WPR + gx + 1] : 0ull;
    }
    hm[rr][cc] = m | (m << 1) | (m << 2) | (m >> 1) | (m >> 2)
                   | (l >> 62) | (l >> 63) | (r << 62) | (r << 63);
  }
  __syncthreads();
  for (int it = tid; it < 64 * 16; it += 256) {
    int rr = it >> 4;
    int cc = it & 15;
    u64 v = hm[rr][cc] | hm[rr + 1][cc] | hm[rr + 2][cc] | hm[rr + 3][cc] | hm[rr + 4][cc];
    out[(r0 + rr) * WPR + c0 + cc] = v;
  }
}

// ---------------------------------------------------------------------------
// 8) fused erode (De Morgan) + unpack to f32: out = 1 - bit(dilate(~d1)).
// ---------------------------------------------------------------------------
__global__ void erode_unpack_kernel(const u64* __restrict__ in, float* __restrict__ out) {
  __shared__ u64 hm[68][16];
  __shared__ u64 d2[64][16];
  int bx = blockIdx.x & 3;
  int by = blockIdx.x >> 2;
  int r0 = by * 64, c0 = bx * 16;
  int tid = threadIdx.x;
  for (int it = tid; it < 68 * 16; it += 256) {
    int rr = it >> 4;
    int cc = it & 15;
    int gy = r0 - 2 + rr;
    int gx = c0 + cc;
    u64 m = 0, l = 0, r = 0;
    if ((unsigned)gy < (unsigned)HH) {
      m = ~in[gy * WPR + gx];
      l = (gx > 0) ? ~in[gy * WPR + gx - 1] : 0ull;
      r = (gx < WPR - 1) ? ~in[gy * WPR + gx + 1] : 0ull;
    }
    hm[rr][cc] = m | (m << 1) | (m << 2) | (m >> 1) | (m >> 2)
                   | (l >> 62) | (l >> 63) | (r << 62) | (r << 63);
  }
  __syncthreads();
  for (int it = tid; it < 64 * 16; it += 256) {
    int rr = it >> 4;
    int cc = it & 15;
    d2[rr][cc] = hm[rr][cc] | hm[rr + 1][cc] | hm[rr + 2][cc] | hm[rr + 3][cc] | hm[rr + 4][cc];
  }
  __syncthreads();
  int colbase = c0 * 64;
  for (int it = tid; it < 64 * 256; it += 256) {
    int rr = it >> 8;
    int px0 = (it & 255) * 4;
    u64 w = d2[rr][px0 >> 6];
    int sh = px0 & 63;
    float4 o;
    o.x = (float)(1 - (int)((w >> (sh + 0)) & 1ull));
    o.y = (float)(1 - (int)((w >> (sh + 1)) & 1ull));
    o.z = (float)(1 - (int)((w >> (sh + 2)) & 1ull));
    o.w = (float)(1 - (int)((w >> (sh + 3)) & 1ull));
    *(float4*)(out + (size_t)(r0 + rr) * WW + colbase + px0) = o;
  }
}

// ---------------------------------------------------------------------------
extern "C" void kernel_launch(void* const* d_in, const int* in_sizes, int n_in,
                              void* d_out, int out_size, void* d_ws, size_t ws_size,
                              hipStream_t stream) {
  const float* x = (const float*)d_in[0];
  if (n_in > 1 && in_sizes[0] != NPIX) x = (const float*)d_in[1];
  float* out = (float*)d_out;
  char* ws = (char*)d_ws;

  // workspace layout — TOTAL ~7.4 MB
  const size_t OFF_HIST = 0;          // 2,097,152
  const size_t OFF_TH   = 2097152;    // 256
  const size_t OFF_PKA  = 2097408;    // 2,097,152
  const size_t OFF_PKB  = 4194560;    // 2,097,152
  const size_t OFF_BCNT = 6291712;    // 256
  const size_t OFF_BINS = 6291968;    // 1,024
  const size_t OFF_VHL  = 6292992;    // 512
  const size_t OFF_BAND = 6293504;    // 1,048,576 (end ~7.34 MB)
  uint32_t* hist    = (uint32_t*)(ws + OFF_HIST);
  float*    th      = (float*)(ws + OFF_TH);
  u64*      PKA     = (u64*)(ws + OFF_PKA);
  u64*      PKB     = (u64*)(ws + OFF_PKB);
  uint32_t* bandcnt = (uint32_t*)(ws + OFF_BCNT);
  int4*     bins4   = (int4*)(ws + OFF_BINS);
  float2*   vhl     = (float2*)(ws + OFF_VHL);
  float*    band    = (float*)(ws + OFF_BAND);

  float* blurred = out;   // blur lives in d_out; erode_unpack rewrites it

  const int TPB = 256;
  const int NB = NPIX / TPB;   // 65536

  hipMemsetAsync(hist, 0, (size_t)NFRAG * NBINS * sizeof(uint32_t), stream);
  hipMemsetAsync(bandcnt, 0, NFRAG * sizeof(uint32_t), stream);
  blur_hist_kernel<<<1024, TPB, 0, stream>>>(x, blurred, hist);
  findcrit_kernel<<<NFRAG, TPB, 0, stream>>>(hist, bins4);
  gather_kernel<<<NB, TPB, 0, stream>>>(blurred, bins4, band, bandcnt);
  select_kernel<<<NFRAG, TPB, 0, stream>>>(band, bandcnt, bins4, vhl);
  walk_kernel<<<1, 64, 0, stream>>>(vhl, th);
  mask_pack_kernel<<<NB, TPB, 0, stream>>>(blurred, th, PKA);
  dilate_kernel<<<256, TPB, 0, stream>>>(PKA, PKB);
  erode_unpack_kernel<<<256, TPB, 0, stream>>>(PKB, out);
}

// Round 14
// 457.419 us; speedup vs baseline: 1.6453x; 1.0452x over previous
//
#include <hip/hip_runtime.h>
#include <stdint.h>

#define HH 4096
#define WW 4096
#define NPIX (HH * WW)
#define NBINS 8192
#define NFRAG 64
#define FRAG_PIX (512 * 512)   // 2^18
#define WPR 64                 // u64 words per row (4096/64)
#define NWORDS (HH * WPR)      // 262144
#define CAP 4096               // per-fragment critical-band capacity

// Reference stop conditions (integer-exact):
//   phase0 stop: cnt >= 31458 <=> th < V_HI,  V_HI = v_sorted[230686]
//   phase1 stop: cnt <= 20971 <=> th >= V_LO, V_LO = v_sorted[241172]
#define RANK_HI 230686u
#define RANK_LO 241172u

typedef unsigned long long u64;

__device__ __forceinline__ int frag_of(int py, int px) {
  return ((py >> 9) << 3) + (px >> 9);
}

__device__ __forceinline__ int bin_of(float v) {
  int b = (int)(v * 8192.0f);   // monotone f32 map
  if (b < 0) b = 0;
  if (b > NBINS - 1) b = NBINS - 1;
  return b;
}

// spread 16 bits so bit i lands at position 4i
__device__ __forceinline__ u64 spread4(u64 x) {
  x &= 0xFFFFull;
  x = (x | (x << 24)) & 0x000000FF000000FFull;
  x = (x | (x << 12)) & 0x000F000F000F000Full;
  x = (x | (x << 6))  & 0x0303030303030303ull;
  x = (x | (x << 3))  & 0x1111111111111111ull;
  return x;
}

// ---------------------------------------------------------------------------
// VERIFIED bit-exact blur tree (numpy pairwise_sum n=25 over materialized
// (windows*k), row-major taps, OOB -> exact 0). DO NOT TOUCH.
// ---------------------------------------------------------------------------
__device__ __forceinline__ float blur_tree(const float rowbuf[5][8], int e) {
  const float K = (float)(1.0 / 25.0);
  float p[25];
#pragma unroll
  for (int i = 0; i < 25; ++i) {
    p[i] = __fmul_rn(rowbuf[i / 5][e + (i % 5)], K);
  }
  float r0 = __fadd_rn(__fadd_rn(p[0], p[8]),  p[16]);
  float r1 = __fadd_rn(__fadd_rn(p[1], p[9]),  p[17]);
  float r2 = __fadd_rn(__fadd_rn(p[2], p[10]), p[18]);
  float r3 = __fadd_rn(__fadd_rn(p[3], p[11]), p[19]);
  float r4 = __fadd_rn(__fadd_rn(p[4], p[12]), p[20]);
  float r5 = __fadd_rn(__fadd_rn(p[5], p[13]), p[21]);
  float r6 = __fadd_rn(__fadd_rn(p[6], p[14]), p[22]);
  float r7 = __fadd_rn(__fadd_rn(p[7], p[15]), p[23]);
  float res = __fadd_rn(
      __fadd_rn(__fadd_rn(r0, r1), __fadd_rn(r2, r3)),
      __fadd_rn(__fadd_rn(r4, r5), __fadd_rn(r6, r7)));
  return __fadd_rn(res, p[24]);
}

// ---------------------------------------------------------------------------
// 1) FUSED blur + per-fragment LDS histogram, vector-loaded (f2+f4+f2 rows).
// ---------------------------------------------------------------------------
__global__ void blur_hist_kernel(const float* __restrict__ x,
                                 float* __restrict__ out,
                                 uint32_t* __restrict__ hist) {
  __shared__ uint32_t lh[NBINS];
  int tid = threadIdx.x;
  for (int i = tid; i < NBINS; i += 256) lh[i] = 0;
  __syncthreads();
  int f = blockIdx.x >> 4;
  int s = blockIdx.x & 15;
  int row0 = (f >> 3) * 512 + s * 32;
  int col0 = (f & 7) * 512;
  for (int it = tid; it < 32 * 128; it += 256) {
    int rr = it >> 7;
    int c4 = it & 127;
    int py = row0 + rr;
    int px = col0 + c4 * 4;
    float rowbuf[5][8];
    bool interior = (px >= 2) && (px + 5 < WW);
#pragma unroll
    for (int r = 0; r < 5; ++r) {
      int yy = py - 2 + r;
      if ((unsigned)yy >= (unsigned)HH) {
#pragma unroll
        for (int j = 0; j < 8; ++j) rowbuf[r][j] = 0.0f;
      } else if (interior) {
        const float* rp = x + (size_t)yy * WW + px;
        float2 L = *(const float2*)(rp - 2);
        float4 M = *(const float4*)(rp);
        float2 R = *(const float2*)(rp + 4);
        rowbuf[r][0] = L.x; rowbuf[r][1] = L.y;
        rowbuf[r][2] = M.x; rowbuf[r][3] = M.y;
        rowbuf[r][4] = M.z; rowbuf[r][5] = M.w;
        rowbuf[r][6] = R.x; rowbuf[r][7] = R.y;
      } else {
#pragma unroll
        for (int j = 0; j < 8; ++j) {
          int xx = px - 2 + j;
          rowbuf[r][j] = ((unsigned)xx < (unsigned)WW) ? x[(size_t)yy * WW + xx] : 0.0f;
        }
      }
    }
    float4 res;
    res.x = blur_tree(rowbuf, 0);
    res.y = blur_tree(rowbuf, 1);
    res.z = blur_tree(rowbuf, 2);
    res.w = blur_tree(rowbuf, 3);
    *(float4*)(out + (size_t)py * WW + px) = res;
    atomicAdd(&lh[bin_of(res.x)], 1u);
    atomicAdd(&lh[bin_of(res.y)], 1u);
    atomicAdd(&lh[bin_of(res.z)], 1u);
    atomicAdd(&lh[bin_of(res.w)], 1u);
  }
  __syncthreads();
  uint32_t* hf = hist + f * NBINS;
  for (int i = tid; i < NBINS; i += 256) {
    uint32_t c = lh[i];
    if (c) atomicAdd(&hf[i], c);
  }
}

// ---------------------------------------------------------------------------
// 2) find critical buckets + local ranks. bins4[f] = (bhi, blo, khi, klo).
// ---------------------------------------------------------------------------
__global__ void findcrit_kernel(const uint32_t* __restrict__ hist,
                                int4* __restrict__ bins4) {
  __shared__ uint32_t segsum[256];
  __shared__ uint32_t segoff[256];
  __shared__ int4 result;
  int f = blockIdx.x;
  int tid = threadIdx.x;
  const uint32_t* hf = hist + f * NBINS;
  int base = tid * 32;
  uint32_t h32[32];
  uint32_t s = 0;
  for (int i = 0; i < 32; ++i) { h32[i] = hf[base + i]; s += h32[i]; }
  segsum[tid] = s;
  __syncthreads();
  if (tid == 0) {
    uint32_t a = 0;
    for (int i = 0; i < 256; ++i) { segoff[i] = a; a += segsum[i]; }
  }
  __syncthreads();
  uint32_t st = segoff[tid];
  uint32_t en = st + segsum[tid];
  if (st <= RANK_HI && RANK_HI < en) {
    uint32_t a = st;
    for (int i = 0; i < 32; ++i) {
      uint32_t nx = a + h32[i];
      if (RANK_HI < nx) { result.x = base + i; result.z = (int)(RANK_HI - a); break; }
      a = nx;
    }
  }
  if (st <= RANK_LO && RANK_LO < en) {
    uint32_t a = st;
    for (int i = 0; i < 32; ++i) {
      uint32_t nx = a + h32[i];
      if (RANK_LO < nx) { result.y = base + i; result.w = (int)(RANK_LO - a); break; }
      a = nx;
    }
  }
  __syncthreads();
  if (tid == 0) bins4[f] = result;
}

// ---------------------------------------------------------------------------
// 3) gather critical-bucket values — float4 vectorized (4 px/thread)
// ---------------------------------------------------------------------------
__global__ void gather_kernel(const float* __restrict__ blur,
                              const int4* __restrict__ bins4,
                              float* __restrict__ band,
                              uint32_t* __restrict__ bandcnt) {
  int t = blockIdx.x * blockDim.x + threadIdx.x;   // 4.19M threads
  int p0 = t * 4;
  int px = p0 & (WW - 1);
  int py = p0 >> 12;
  int f = frag_of(py, px);   // constant across the 4 px (512-col aligned)
  int4 info = bins4[f];
  float4 v4 = *(const float4*)(blur + p0);
  float vv[4] = {v4.x, v4.y, v4.z, v4.w};
#pragma unroll
  for (int e = 0; e < 4; ++e) {
    int b = bin_of(vv[e]);
    if (b == info.x || b == info.y) {
      uint32_t pos = atomicAdd(&bandcnt[f], 1u);
      if (pos < CAP) band[(size_t)f * CAP + pos] = vv[e];
    }
  }
}

// ---------------------------------------------------------------------------
// 4) exact order-statistic selection within the critical buckets
// ---------------------------------------------------------------------------
__global__ void select_kernel(const float* __restrict__ band,
                              const uint32_t* __restrict__ bandcnt,
                              const int4* __restrict__ bins4,
                              float2* __restrict__ vhl) {
  __shared__ float wv[CAP];
  __shared__ float res[2];
  int f = blockIdx.x;
  int tid = threadIdx.x;
  int n = (int)bandcnt[f];
  if (n > CAP) n = CAP;
  for (int i = tid; i < n; i += 256) wv[i] = band[(size_t)f * CAP + i];
  __syncthreads();
  int4 info = bins4[f];
#pragma unroll
  for (int sel = 0; sel < 2; ++sel) {
    int tb = sel ? info.y : info.x;
    int k  = sel ? info.w : info.z;
    for (int i = tid; i < n; i += 256) {
      float w = wv[i];
      if (bin_of(w) != tb) continue;
      int less = 0, leq = 0;
      for (int j = 0; j < n; ++j) {
        float u = wv[j];
        if (bin_of(u) == tb) {
          less += (u < w) ? 1 : 0;
          leq  += (u <= w) ? 1 : 0;
        }
      }
      if (less <= k && k < leq) res[sel] = w;   // unique value; benign race
    }
  }
  __syncthreads();
  if (tid == 0) vhl[f] = make_float2(res[0], res[1]);
}

// ---------------------------------------------------------------------------
// 5) threshold walk — reference's scalar while-loops (uniform, one wave)
// ---------------------------------------------------------------------------
__global__ void walk_kernel(const float2* __restrict__ vhl, float* __restrict__ th_out) {
  int lane = threadIdx.x;
  float2 mine = vhl[lane];   // lane f holds fragment f's (V_HI, V_LO)
  float th = 0.5f;           // TH1_INIT
  for (int f = 0; f < NFRAG; ++f) {
    float VH = __shfl(mine.x, f);
    float VL = __shfl(mine.y, f);
    while (th >= VH) th = __fadd_rn(th, -0.0005f);
    while (th <  VL) th = __fadd_rn(th,  0.0005f);
    if (lane == 0) th_out[f] = th;
  }
}

// ---------------------------------------------------------------------------
// 6) mask + bit-pack — float4 vectorized (4 px/thread, 4-way ballot interleave)
//    pixel p = lane*4+e of the wave; word w bit j <=> j = 4*(L-16w)+e.
// ---------------------------------------------------------------------------
__global__ void mask_pack_kernel(const float* __restrict__ blur,
                                 const float* __restrict__ th,
                                 u64* __restrict__ pk) {
  int t = blockIdx.x * blockDim.x + threadIdx.x;   // 4.19M threads
  int p0 = t * 4;
  int px = p0 & (WW - 1);
  int py = p0 >> 12;
  float tf = th[frag_of(py, px)];
  float4 v4 = *(const float4*)(blur + p0);
  u64 b0 = __ballot(v4.x > tf);
  u64 b1 = __ballot(v4.y > tf);
  u64 b2 = __ballot(v4.z > tf);
  u64 b3 = __ballot(v4.w > tf);
  int lane = threadIdx.x & 63;
  if ((lane & 15) == 0) {
    int sh = lane;                 // 0,16,32,48
    u64 w = spread4(b0 >> sh) | (spread4(b1 >> sh) << 1)
          | (spread4(b2 >> sh) << 2) | (spread4(b3 >> sh) << 3);
    // wave base pixel = (t - lane)*4 ; word index = base/64 + lane/16
    int base_word = ((t - lane) * 4) >> 6;
    pk[base_word + (lane >> 4)] = w;
  }
}

// ---------------------------------------------------------------------------
// 7) fused dilate (H+V) on packed bits; OOB = 0 (clipped window).
// ---------------------------------------------------------------------------
__global__ void dilate_kernel(const u64* __restrict__ in, u64* __restrict__ out) {
  __shared__ u64 hm[68][16];
  int bx = blockIdx.x & 3;
  int by = blockIdx.x >> 2;
  int r0 = by * 64, c0 = bx * 16;
  int tid = threadIdx.x;
  for (int it = tid; it < 68 * 16; it += 256) {
    int rr = it >> 4;
    int cc = it & 15;
    int gy = r0 - 2 + rr;
    int gx = c0 + cc;
    u64 m = 0, l = 0, r = 0;
    if ((unsigned)gy < (unsigned)HH) {
      m = in[gy * WPR + gx];
      l = (gx > 0) ? in[gy * WPR + gx - 1] : 0ull;
      r = (gx < WPR - 1) ? in[gy * WPR + gx + 1] : 0ull;
    }
    hm[rr][cc] = m | (m << 1) | (m << 2) | (m >> 1) | (m >> 2)
                   | (l >> 62) | (l >> 63) | (r << 62) | (r << 63);
  }
  __syncthreads();
  for (int it = tid; it < 64 * 16; it += 256) {
    int rr = it >> 4;
    int cc = it & 15;
    u64 v = hm[rr][cc] | hm[rr + 1][cc] | hm[rr + 2][cc] | hm[rr + 3][cc] | hm[rr + 4][cc];
    out[(r0 + rr) * WPR + c0 + cc] = v;
  }
}

// ---------------------------------------------------------------------------
// 8) fused erode (De Morgan) + unpack to f32: out = 1 - bit(dilate(~d1)).
// ---------------------------------------------------------------------------
__global__ void erode_unpack_kernel(const u64* __restrict__ in, float* __restrict__ out) {
  __shared__ u64 hm[68][16];
  __shared__ u64 d2[64][16];
  int bx = blockIdx.x & 3;
  int by = blockIdx.x >> 2;
  int r0 = by * 64, c0 = bx * 16;
  int tid = threadIdx.x;
  for (int it = tid; it < 68 * 16; it += 256) {
    int rr = it >> 4;
    int cc = it & 15;
    int gy = r0 - 2 + rr;
    int gx = c0 + cc;
    u64 m = 0, l = 0, r = 0;
    if ((unsigned)gy < (unsigned)HH) {
      m = ~in[gy * WPR + gx];
      l = (gx > 0) ? ~in[gy * WPR + gx - 1] : 0ull;
      r = (gx < WPR - 1) ? ~in[gy * WPR + gx + 1] : 0ull;
    }
    hm[rr][cc] = m | (m << 1) | (m << 2) | (m >> 1) | (m >> 2)
                   | (l >> 62) | (l >> 63) | (r << 62) | (r << 63);
  }
  __syncthreads();
  for (int it = tid; it < 64 * 16; it += 256) {
    int rr = it >> 4;
    int cc = it & 15;
    d2[rr][cc] = hm[rr][cc] | hm[rr + 1][cc] | hm[rr + 2][cc] | hm[rr + 3][cc] | hm[rr + 4][cc];
  }
  __syncthreads();
  int colbase = c0 * 64;
  for (int it = tid; it < 64 * 256; it += 256) {
    int rr = it >> 8;
    int px0 = (it & 255) * 4;
    u64 w = d2[rr][px0 >> 6];
    int sh = px0 & 63;
    float4 o;
    o.x = (float)(1 - (int)((w >> (sh + 0)) & 1ull));
    o.y = (float)(1 - (int)((w >> (sh + 1)) & 1ull));
    o.z = (float)(1 - (int)((w >> (sh + 2)) & 1ull));
    o.w = (float)(1 - (int)((w >> (sh + 3)) & 1ull));
    *(float4*)(out + (size_t)(r0 + rr) * WW + colbase + px0) = o;
  }
}

// ---------------------------------------------------------------------------
extern "C" void kernel_launch(void* const* d_in, const int* in_sizes, int n_in,
                              void* d_out, int out_size, void* d_ws, size_t ws_size,
                              hipStream_t stream) {
  const float* x = (const float*)d_in[0];
  if (n_in > 1 && in_sizes[0] != NPIX) x = (const float*)d_in[1];
  float* out = (float*)d_out;
  char* ws = (char*)d_ws;

  // workspace layout — TOTAL ~7.4 MB
  const size_t OFF_HIST = 0;          // 2,097,152
  const size_t OFF_TH   = 2097152;    // 256
  const size_t OFF_PKA  = 2097408;    // 2,097,152
  const size_t OFF_PKB  = 4194560;    // 2,097,152
  const size_t OFF_BCNT = 6291712;    // 256
  const size_t OFF_BINS = 6291968;    // 1,024
  const size_t OFF_VHL  = 6292992;    // 512
  const size_t OFF_BAND = 6293504;    // 1,048,576 (end ~7.34 MB)
  uint32_t* hist    = (uint32_t*)(ws + OFF_HIST);
  float*    th      = (float*)(ws + OFF_TH);
  u64*      PKA     = (u64*)(ws + OFF_PKA);
  u64*      PKB     = (u64*)(ws + OFF_PKB);
  uint32_t* bandcnt = (uint32_t*)(ws + OFF_BCNT);
  int4*     bins4   = (int4*)(ws + OFF_BINS);
  float2*   vhl     = (float2*)(ws + OFF_VHL);
  float*    band    = (float*)(ws + OFF_BAND);

  float* blurred = out;   // blur lives in d_out; erode_unpack rewrites it

  const int TPB = 256;
  const int NB4 = NPIX / 4 / TPB;   // 16384

  hipMemsetAsync(hist, 0, (size_t)NFRAG * NBINS * sizeof(uint32_t), stream);
  hipMemsetAsync(bandcnt, 0, NFRAG * sizeof(uint32_t), stream);
  blur_hist_kernel<<<1024, TPB, 0, stream>>>(x, blurred, hist);
  findcrit_kernel<<<NFRAG, TPB, 0, stream>>>(hist, bins4);
  gather_kernel<<<NB4, TPB, 0, stream>>>(blurred, bins4, band, bandcnt);
  select_kernel<<<NFRAG, TPB, 0, stream>>>(band, bandcnt, bins4, vhl);
  walk_kernel<<<1, 64, 0, stream>>>(vhl, th);
  mask_pack_kernel<<<NB4, TPB, 0, stream>>>(blurred, th, PKA);
  dilate_kernel<<<256, TPB, 0, stream>>>(PKA, PKB);
  erode_unpack_kernel<<<256, TPB, 0, stream>>>(PKB, out);
}

// Round 15
// 412.162 us; speedup vs baseline: 1.8259x; 1.1098x over previous
//
#include <hip/hip_runtime.h>
#include <stdint.h>

#define HH 4096
#define WW 4096
#define NPIX (HH * WW)
#define NBINS 8192
#define NFRAG 64
#define FRAG_PIX (512 * 512)   // 2^18
#define WPR 64                 // u64 words per row (4096/64)
#define NWORDS (HH * WPR)      // 262144
#define CAP 4096               // per-fragment critical-band capacity

// Reference stop conditions (integer-exact):
//   phase0 stop: cnt >= 31458 <=> th < V_HI,  V_HI = v_sorted[230686]
//   phase1 stop: cnt <= 20971 <=> th >= V_LO, V_LO = v_sorted[241172]
#define RANK_HI 230686u
#define RANK_LO 241172u

typedef unsigned long long u64;

__device__ __forceinline__ int frag_of(int py, int px) {
  return ((py >> 9) << 3) + (px >> 9);
}

__device__ __forceinline__ int bin_of(float v) {
  int b = (int)(v * 8192.0f);   // monotone f32 map
  if (b < 0) b = 0;
  if (b > NBINS - 1) b = NBINS - 1;
  return b;
}

// spread 16 bits so bit i lands at position 4i
__device__ __forceinline__ u64 spread4(u64 x) {
  x &= 0xFFFFull;
  x = (x | (x << 24)) & 0x000000FF000000FFull;
  x = (x | (x << 12)) & 0x000F000F000F000Full;
  x = (x | (x << 6))  & 0x0303030303030303ull;
  x = (x | (x << 3))  & 0x1111111111111111ull;
  return x;
}

// ---------------------------------------------------------------------------
// VERIFIED bit-exact blur tree (numpy pairwise_sum n=25 over materialized
// (windows*k), row-major taps, OOB -> exact 0). DO NOT TOUCH.
// ---------------------------------------------------------------------------
__device__ __forceinline__ float blur_tree(const float rowbuf[5][8], int e) {
  const float K = (float)(1.0 / 25.0);
  float p[25];
#pragma unroll
  for (int i = 0; i < 25; ++i) {
    p[i] = __fmul_rn(rowbuf[i / 5][e + (i % 5)], K);
  }
  float r0 = __fadd_rn(__fadd_rn(p[0], p[8]),  p[16]);
  float r1 = __fadd_rn(__fadd_rn(p[1], p[9]),  p[17]);
  float r2 = __fadd_rn(__fadd_rn(p[2], p[10]), p[18]);
  float r3 = __fadd_rn(__fadd_rn(p[3], p[11]), p[19]);
  float r4 = __fadd_rn(__fadd_rn(p[4], p[12]), p[20]);
  float r5 = __fadd_rn(__fadd_rn(p[5], p[13]), p[21]);
  float r6 = __fadd_rn(__fadd_rn(p[6], p[14]), p[22]);
  float r7 = __fadd_rn(__fadd_rn(p[7], p[15]), p[23]);
  float res = __fadd_rn(
      __fadd_rn(__fadd_rn(r0, r1), __fadd_rn(r2, r3)),
      __fadd_rn(__fadd_rn(r4, r5), __fadd_rn(r6, r7)));
  return __fadd_rn(res, p[24]);
}

// ---------------------------------------------------------------------------
// 1) FUSED blur + per-fragment LDS histogram, vector-loaded (f2+f4+f2 rows).
// ---------------------------------------------------------------------------
__global__ void blur_hist_kernel(const float* __restrict__ x,
                                 float* __restrict__ out,
                                 uint32_t* __restrict__ hist) {
  __shared__ uint32_t lh[NBINS];
  int tid = threadIdx.x;
  for (int i = tid; i < NBINS; i += 256) lh[i] = 0;
  __syncthreads();
  int f = blockIdx.x >> 4;
  int s = blockIdx.x & 15;
  int row0 = (f >> 3) * 512 + s * 32;
  int col0 = (f & 7) * 512;
  for (int it = tid; it < 32 * 128; it += 256) {
    int rr = it >> 7;
    int c4 = it & 127;
    int py = row0 + rr;
    int px = col0 + c4 * 4;
    float rowbuf[5][8];
    bool interior = (px >= 2) && (px + 5 < WW);
#pragma unroll
    for (int r = 0; r < 5; ++r) {
      int yy = py - 2 + r;
      if ((unsigned)yy >= (unsigned)HH) {
#pragma unroll
        for (int j = 0; j < 8; ++j) rowbuf[r][j] = 0.0f;
      } else if (interior) {
        const float* rp = x + (size_t)yy * WW + px;
        float2 L = *(const float2*)(rp - 2);
        float4 M = *(const float4*)(rp);
        float2 R = *(const float2*)(rp + 4);
        rowbuf[r][0] = L.x; rowbuf[r][1] = L.y;
        rowbuf[r][2] = M.x; rowbuf[r][3] = M.y;
        rowbuf[r][4] = M.z; rowbuf[r][5] = M.w;
        rowbuf[r][6] = R.x; rowbuf[r][7] = R.y;
      } else {
#pragma unroll
        for (int j = 0; j < 8; ++j) {
          int xx = px - 2 + j;
          rowbuf[r][j] = ((unsigned)xx < (unsigned)WW) ? x[(size_t)yy * WW + xx] : 0.0f;
        }
      }
    }
    float4 res;
    res.x = blur_tree(rowbuf, 0);
    res.y = blur_tree(rowbuf, 1);
    res.z = blur_tree(rowbuf, 2);
    res.w = blur_tree(rowbuf, 3);
    *(float4*)(out + (size_t)py * WW + px) = res;
    atomicAdd(&lh[bin_of(res.x)], 1u);
    atomicAdd(&lh[bin_of(res.y)], 1u);
    atomicAdd(&lh[bin_of(res.z)], 1u);
    atomicAdd(&lh[bin_of(res.w)], 1u);
  }
  __syncthreads();
  uint32_t* hf = hist + f * NBINS;
  for (int i = tid; i < NBINS; i += 256) {
    uint32_t c = lh[i];
    if (c) atomicAdd(&hf[i], c);
  }
}

// ---------------------------------------------------------------------------
// 2) find critical buckets + local ranks. bins4[f] = (bhi, blo, khi, klo).
// ---------------------------------------------------------------------------
__global__ void findcrit_kernel(const uint32_t* __restrict__ hist,
                                int4* __restrict__ bins4) {
  __shared__ uint32_t segsum[256];
  __shared__ uint32_t segoff[256];
  __shared__ int4 result;
  int f = blockIdx.x;
  int tid = threadIdx.x;
  const uint32_t* hf = hist + f * NBINS;
  int base = tid * 32;
  uint32_t h32[32];
  uint32_t s = 0;
  for (int i = 0; i < 32; ++i) { h32[i] = hf[base + i]; s += h32[i]; }
  segsum[tid] = s;
  __syncthreads();
  if (tid == 0) {
    uint32_t a = 0;
    for (int i = 0; i < 256; ++i) { segoff[i] = a; a += segsum[i]; }
  }
  __syncthreads();
  uint32_t st = segoff[tid];
  uint32_t en = st + segsum[tid];
  if (st <= RANK_HI && RANK_HI < en) {
    uint32_t a = st;
    for (int i = 0; i < 32; ++i) {
      uint32_t nx = a + h32[i];
      if (RANK_HI < nx) { result.x = base + i; result.z = (int)(RANK_HI - a); break; }
      a = nx;
    }
  }
  if (st <= RANK_LO && RANK_LO < en) {
    uint32_t a = st;
    for (int i = 0; i < 32; ++i) {
      uint32_t nx = a + h32[i];
      if (RANK_LO < nx) { result.y = base + i; result.w = (int)(RANK_LO - a); break; }
      a = nx;
    }
  }
  __syncthreads();
  if (tid == 0) bins4[f] = result;
}

// ---------------------------------------------------------------------------
// 3) gather critical-bucket values — 16 px/thread, 4 hoisted float4 loads
//    (4x memory-level parallelism; each load instruction lane-coalesced)
// ---------------------------------------------------------------------------
__global__ void gather_kernel(const float* __restrict__ blur,
                              const int4* __restrict__ bins4,
                              float* __restrict__ band,
                              uint32_t* __restrict__ bandcnt) {
  const int T = NPIX / 16;   // 1,048,576 threads
  int t = blockIdx.x * blockDim.x + threadIdx.x;
  float4 v[4];
#pragma unroll
  for (int k = 0; k < 4; ++k) {
    v[k] = *(const float4*)(blur + (size_t)(t + k * T) * 4);
  }
#pragma unroll
  for (int k = 0; k < 4; ++k) {
    int p0 = (t + k * T) * 4;
    int f = frag_of(p0 >> 12, p0 & (WW - 1));
    int4 info = bins4[f];
    float vv[4] = {v[k].x, v[k].y, v[k].z, v[k].w};
#pragma unroll
    for (int e = 0; e < 4; ++e) {
      int b = bin_of(vv[e]);
      if (b == info.x || b == info.y) {
        uint32_t pos = atomicAdd(&bandcnt[f], 1u);
        if (pos < CAP) band[(size_t)f * CAP + pos] = vv[e];
      }
    }
  }
}

// ---------------------------------------------------------------------------
// 4) exact order-statistic selection within the critical buckets
// ---------------------------------------------------------------------------
__global__ void select_kernel(const float* __restrict__ band,
                              const uint32_t* __restrict__ bandcnt,
                              const int4* __restrict__ bins4,
                              float2* __restrict__ vhl) {
  __shared__ float wv[CAP];
  __shared__ float res[2];
  int f = blockIdx.x;
  int tid = threadIdx.x;
  int n = (int)bandcnt[f];
  if (n > CAP) n = CAP;
  for (int i = tid; i < n; i += 256) wv[i] = band[(size_t)f * CAP + i];
  __syncthreads();
  int4 info = bins4[f];
#pragma unroll
  for (int sel = 0; sel < 2; ++sel) {
    int tb = sel ? info.y : info.x;
    int k  = sel ? info.w : info.z;
    for (int i = tid; i < n; i += 256) {
      float w = wv[i];
      if (bin_of(w) != tb) continue;
      int less = 0, leq = 0;
      for (int j = 0; j < n; ++j) {
        float u = wv[j];
        if (bin_of(u) == tb) {
          less += (u < w) ? 1 : 0;
          leq  += (u <= w) ? 1 : 0;
        }
      }
      if (less <= k && k < leq) res[sel] = w;   // unique value; benign race
    }
  }
  __syncthreads();
  if (tid == 0) vhl[f] = make_float2(res[0], res[1]);
}

// ---------------------------------------------------------------------------
// 5) threshold walk — reference's scalar while-loops (uniform, one wave)
// ---------------------------------------------------------------------------
__global__ void walk_kernel(const float2* __restrict__ vhl, float* __restrict__ th_out) {
  int lane = threadIdx.x;
  float2 mine = vhl[lane];   // lane f holds fragment f's (V_HI, V_LO)
  float th = 0.5f;           // TH1_INIT
  for (int f = 0; f < NFRAG; ++f) {
    float VH = __shfl(mine.x, f);
    float VL = __shfl(mine.y, f);
    while (th >= VH) th = __fadd_rn(th, -0.0005f);
    while (th <  VL) th = __fadd_rn(th,  0.0005f);
    if (lane == 0) th_out[f] = th;
  }
}

// ---------------------------------------------------------------------------
// 6) mask + bit-pack — 16 px/thread, 4 hoisted float4 loads, ballot interleave
//    per 4-px group (bit layout identical to R14).
// ---------------------------------------------------------------------------
__global__ void mask_pack_kernel(const float* __restrict__ blur,
                                 const float* __restrict__ th,
                                 u64* __restrict__ pk) {
  const int T = NPIX / 16;   // 1,048,576 threads
  int t = blockIdx.x * blockDim.x + threadIdx.x;
  float4 v[4];
#pragma unroll
  for (int k = 0; k < 4; ++k) {
    v[k] = *(const float4*)(blur + (size_t)(t + k * T) * 4);
  }
  int lane = threadIdx.x & 63;
#pragma unroll
  for (int k = 0; k < 4; ++k) {
    int g = t + k * T;           // 4-px group index
    int p0 = g * 4;
    float tf = th[frag_of(p0 >> 12, p0 & (WW - 1))];
    u64 b0 = __ballot(v[k].x > tf);
    u64 b1 = __ballot(v[k].y > tf);
    u64 b2 = __ballot(v[k].z > tf);
    u64 b3 = __ballot(v[k].w > tf);
    if ((lane & 15) == 0) {
      int sh = lane;             // 0,16,32,48
      u64 w = spread4(b0 >> sh) | (spread4(b1 >> sh) << 1)
            | (spread4(b2 >> sh) << 2) | (spread4(b3 >> sh) << 3);
      int base_word = ((g - lane) * 4) >> 6;
      pk[base_word + (lane >> 4)] = w;
    }
  }
}

// ---------------------------------------------------------------------------
// 7) fused dilate (H+V) on packed bits; OOB = 0 (clipped window).
// ---------------------------------------------------------------------------
__global__ void dilate_kernel(const u64* __restrict__ in, u64* __restrict__ out) {
  __shared__ u64 hm[68][16];
  int bx = blockIdx.x & 3;
  int by = blockIdx.x >> 2;
  int r0 = by * 64, c0 = bx * 16;
  int tid = threadIdx.x;
  for (int it = tid; it < 68 * 16; it += 256) {
    int rr = it >> 4;
    int cc = it & 15;
    int gy = r0 - 2 + rr;
    int gx = c0 + cc;
    u64 m = 0, l = 0, r = 0;
    if ((unsigned)gy < (unsigned)HH) {
      m = in[gy * WPR + gx];
      l = (gx > 0) ? in[gy * WPR + gx - 1] : 0ull;
      r = (gx < WPR - 1) ? in[gy * WPR + gx + 1] : 0ull;
    }
    hm[rr][cc] = m | (m << 1) | (m << 2) | (m >> 1) | (m >> 2)
                   | (l >> 62) | (l >> 63) | (r << 62) | (r << 63);
  }
  __syncthreads();
  for (int it = tid; it < 64 * 16; it += 256) {
    int rr = it >> 4;
    int cc = it & 15;
    u64 v = hm[rr][cc] | hm[rr + 1][cc] | hm[rr + 2][cc] | hm[rr + 3][cc] | hm[rr + 4][cc];
    out[(r0 + rr) * WPR + c0 + cc] = v;
  }
}

// ---------------------------------------------------------------------------
// 8) fused erode (De Morgan) + unpack to f32: out = 1 - bit(dilate(~d1)).
// ---------------------------------------------------------------------------
__global__ void erode_unpack_kernel(const u64* __restrict__ in, float* __restrict__ out) {
  __shared__ u64 hm[68][16];
  __shared__ u64 d2[64][16];
  int bx = blockIdx.x & 3;
  int by = blockIdx.x >> 2;
  int r0 = by * 64, c0 = bx * 16;
  int tid = threadIdx.x;
  for (int it = tid; it < 68 * 16; it += 256) {
    int rr = it >> 4;
    int cc = it & 15;
    int gy = r0 - 2 + rr;
    int gx = c0 + cc;
    u64 m = 0, l = 0, r = 0;
    if ((unsigned)gy < (unsigned)HH) {
      m = ~in[gy * WPR + gx];
      l = (gx > 0) ? ~in[gy * WPR + gx - 1] : 0ull;
      r = (gx < WPR - 1) ? ~in[gy * WPR + gx + 1] : 0ull;
    }
    hm[rr][cc] = m | (m << 1) | (m << 2) | (m >> 1) | (m >> 2)
                   | (l >> 62) | (l >> 63) | (r << 62) | (r << 63);
  }
  __syncthreads();
  for (int it = tid; it < 64 * 16; it += 256) {
    int rr = it >> 4;
    int cc = it & 15;
    d2[rr][cc] = hm[rr][cc] | hm[rr + 1][cc] | hm[rr + 2][cc] | hm[rr + 3][cc] | hm[rr + 4][cc];
  }
  __syncthreads();
  int colbase = c0 * 64;
  for (int it = tid; it < 64 * 256; it += 256) {
    int rr = it >> 8;
    int px0 = (it & 255) * 4;
    u64 w = d2[rr][px0 >> 6];
    int sh = px0 & 63;
    float4 o;
    o.x = (float)(1 - (int)((w >> (sh + 0)) & 1ull));
    o.y = (float)(1 - (int)((w >> (sh + 1)) & 1ull));
    o.z = (float)(1 - (int)((w >> (sh + 2)) & 1ull));
    o.w = (float)(1 - (int)((w >> (sh + 3)) & 1ull));
    *(float4*)(out + (size_t)(r0 + rr) * WW + colbase + px0) = o;
  }
}

// ---------------------------------------------------------------------------
extern "C" void kernel_launch(void* const* d_in, const int* in_sizes, int n_in,
                              void* d_out, int out_size, void* d_ws, size_t ws_size,
                              hipStream_t stream) {
  const float* x = (const float*)d_in[0];
  if (n_in > 1 && in_sizes[0] != NPIX) x = (const float*)d_in[1];
  float* out = (float*)d_out;
  char* ws = (char*)d_ws;

  // workspace layout — TOTAL ~7.4 MB
  const size_t OFF_HIST = 0;          // 2,097,152
  const size_t OFF_TH   = 2097152;    // 256
  const size_t OFF_PKA  = 2097408;    // 2,097,152
  const size_t OFF_PKB  = 4194560;    // 2,097,152
  const size_t OFF_BCNT = 6291712;    // 256
  const size_t OFF_BINS = 6291968;    // 1,024
  const size_t OFF_VHL  = 6292992;    // 512
  const size_t OFF_BAND = 6293504;    // 1,048,576 (end ~7.34 MB)
  uint32_t* hist    = (uint32_t*)(ws + OFF_HIST);
  float*    th      = (float*)(ws + OFF_TH);
  u64*      PKA     = (u64*)(ws + OFF_PKA);
  u64*      PKB     = (u64*)(ws + OFF_PKB);
  uint32_t* bandcnt = (uint32_t*)(ws + OFF_BCNT);
  int4*     bins4   = (int4*)(ws + OFF_BINS);
  float2*   vhl     = (float2*)(ws + OFF_VHL);
  float*    band    = (float*)(ws + OFF_BAND);

  float* blurred = out;   // blur lives in d_out; erode_unpack rewrites it

  const int TPB = 256;
  const int NB16 = NPIX / 16 / TPB;   // 4096 blocks (16 px/thread kernels)

  hipMemsetAsync(hist, 0, (size_t)NFRAG * NBINS * sizeof(uint32_t), stream);
  hipMemsetAsync(bandcnt, 0, NFRAG * sizeof(uint32_t), stream);
  blur_hist_kernel<<<1024, TPB, 0, stream>>>(x, blurred, hist);
  findcrit_kernel<<<NFRAG, TPB, 0, stream>>>(hist, bins4);
  gather_kernel<<<NB16, TPB, 0, stream>>>(blurred, bins4, band, bandcnt);
  select_kernel<<<NFRAG, TPB, 0, stream>>>(band, bandcnt, bins4, vhl);
  walk_kernel<<<1, 64, 0, stream>>>(vhl, th);
  mask_pack_kernel<<<NB16, TPB, 0, stream>>>(blurred, th, PKA);
  dilate_kernel<<<256, TPB, 0, stream>>>(PKA, PKB);
  erode_unpack_kernel<<<256, TPB, 0, stream>>>(PKB, out);
}

// Round 16
// 357.897 us; speedup vs baseline: 2.1028x; 1.1516x over previous
//
#include <hip/hip_runtime.h>
#include <stdint.h>

#define HH 4096
#define WW 4096
#define NPIX (HH * WW)
#define NBINS 8192
#define NFRAG 64
#define FRAG_PIX (512 * 512)   // 2^18
#define WPR 64                 // u64 words per row (4096/64)
#define NWORDS (HH * WPR)      // 262144
#define CAP 4096               // per-fragment critical-band capacity

// Reference stop conditions (integer-exact):
//   phase0 stop: cnt >= 31458 <=> th < V_HI,  V_HI = v_sorted[230686]
//   phase1 stop: cnt <= 20971 <=> th >= V_LO, V_LO = v_sorted[241172]
#define RANK_HI 230686u
#define RANK_LO 241172u

typedef unsigned long long u64;

__device__ __forceinline__ int frag_of(int py, int px) {
  return ((py >> 9) << 3) + (px >> 9);
}

__device__ __forceinline__ int bin_of(float v) {
  int b = (int)(v * 8192.0f);   // monotone f32 map
  if (b < 0) b = 0;
  if (b > NBINS - 1) b = NBINS - 1;
  return b;
}

// spread 16 bits so bit i lands at position 4i
__device__ __forceinline__ u64 spread4(u64 x) {
  x &= 0xFFFFull;
  x = (x | (x << 24)) & 0x000000FF000000FFull;
  x = (x | (x << 12)) & 0x000F000F000F000Full;
  x = (x | (x << 6))  & 0x0303030303030303ull;
  x = (x | (x << 3))  & 0x1111111111111111ull;
  return x;
}

// ---------------------------------------------------------------------------
// VERIFIED bit-exact blur tree (numpy pairwise_sum n=25 over materialized
// (windows*k), row-major taps, OOB -> exact 0). DO NOT TOUCH.
// ---------------------------------------------------------------------------
__device__ __forceinline__ float blur_tree(const float rowbuf[5][8], int e) {
  const float K = (float)(1.0 / 25.0);
  float p[25];
#pragma unroll
  for (int i = 0; i < 25; ++i) {
    p[i] = __fmul_rn(rowbuf[i / 5][e + (i % 5)], K);
  }
  float r0 = __fadd_rn(__fadd_rn(p[0], p[8]),  p[16]);
  float r1 = __fadd_rn(__fadd_rn(p[1], p[9]),  p[17]);
  float r2 = __fadd_rn(__fadd_rn(p[2], p[10]), p[18]);
  float r3 = __fadd_rn(__fadd_rn(p[3], p[11]), p[19]);
  float r4 = __fadd_rn(__fadd_rn(p[4], p[12]), p[20]);
  float r5 = __fadd_rn(__fadd_rn(p[5], p[13]), p[21]);
  float r6 = __fadd_rn(__fadd_rn(p[6], p[14]), p[22]);
  float r7 = __fadd_rn(__fadd_rn(p[7], p[15]), p[23]);
  float res = __fadd_rn(
      __fadd_rn(__fadd_rn(r0, r1), __fadd_rn(r2, r3)),
      __fadd_rn(__fadd_rn(r4, r5), __fadd_rn(r6, r7)));
  return __fadd_rn(res, p[24]);
}

// ---------------------------------------------------------------------------
// 1) FUSED blur + per-fragment LDS histogram, vector-loaded (f2+f4+f2 rows).
// ---------------------------------------------------------------------------
__global__ void blur_hist_kernel(const float* __restrict__ x,
                                 float* __restrict__ out,
                                 uint32_t* __restrict__ hist) {
  __shared__ uint32_t lh[NBINS];
  int tid = threadIdx.x;
  for (int i = tid; i < NBINS; i += 256) lh[i] = 0;
  __syncthreads();
  int f = blockIdx.x >> 4;
  int s = blockIdx.x & 15;
  int row0 = (f >> 3) * 512 + s * 32;
  int col0 = (f & 7) * 512;
  for (int it = tid; it < 32 * 128; it += 256) {
    int rr = it >> 7;
    int c4 = it & 127;
    int py = row0 + rr;
    int px = col0 + c4 * 4;
    float rowbuf[5][8];
    bool interior = (px >= 2) && (px + 5 < WW);
#pragma unroll
    for (int r = 0; r < 5; ++r) {
      int yy = py - 2 + r;
      if ((unsigned)yy >= (unsigned)HH) {
#pragma unroll
        for (int j = 0; j < 8; ++j) rowbuf[r][j] = 0.0f;
      } else if (interior) {
        const float* rp = x + (size_t)yy * WW + px;
        float2 L = *(const float2*)(rp - 2);
        float4 M = *(const float4*)(rp);
        float2 R = *(const float2*)(rp + 4);
        rowbuf[r][0] = L.x; rowbuf[r][1] = L.y;
        rowbuf[r][2] = M.x; rowbuf[r][3] = M.y;
        rowbuf[r][4] = M.z; rowbuf[r][5] = M.w;
        rowbuf[r][6] = R.x; rowbuf[r][7] = R.y;
      } else {
#pragma unroll
        for (int j = 0; j < 8; ++j) {
          int xx = px - 2 + j;
          rowbuf[r][j] = ((unsigned)xx < (unsigned)WW) ? x[(size_t)yy * WW + xx] : 0.0f;
        }
      }
    }
    float4 res;
    res.x = blur_tree(rowbuf, 0);
    res.y = blur_tree(rowbuf, 1);
    res.z = blur_tree(rowbuf, 2);
    res.w = blur_tree(rowbuf, 3);
    *(float4*)(out + (size_t)py * WW + px) = res;
    atomicAdd(&lh[bin_of(res.x)], 1u);
    atomicAdd(&lh[bin_of(res.y)], 1u);
    atomicAdd(&lh[bin_of(res.z)], 1u);
    atomicAdd(&lh[bin_of(res.w)], 1u);
  }
  __syncthreads();
  uint32_t* hf = hist + f * NBINS;
  for (int i = tid; i < NBINS; i += 256) {
    uint32_t c = lh[i];
    if (c) atomicAdd(&hf[i], c);
  }
}

// ---------------------------------------------------------------------------
// 2) find critical buckets + local ranks. bins4[f] = (bhi, blo, khi, klo).
// ---------------------------------------------------------------------------
__global__ void findcrit_kernel(const uint32_t* __restrict__ hist,
                                int4* __restrict__ bins4) {
  __shared__ uint32_t segsum[256];
  __shared__ uint32_t segoff[256];
  __shared__ int4 result;
  int f = blockIdx.x;
  int tid = threadIdx.x;
  const uint32_t* hf = hist + f * NBINS;
  int base = tid * 32;
  uint32_t h32[32];
  uint32_t s = 0;
  for (int i = 0; i < 32; ++i) { h32[i] = hf[base + i]; s += h32[i]; }
  segsum[tid] = s;
  __syncthreads();
  if (tid == 0) {
    uint32_t a = 0;
    for (int i = 0; i < 256; ++i) { segoff[i] = a; a += segsum[i]; }
  }
  __syncthreads();
  uint32_t st = segoff[tid];
  uint32_t en = st + segsum[tid];
  if (st <= RANK_HI && RANK_HI < en) {
    uint32_t a = st;
    for (int i = 0; i < 32; ++i) {
      uint32_t nx = a + h32[i];
      if (RANK_HI < nx) { result.x = base + i; result.z = (int)(RANK_HI - a); break; }
      a = nx;
    }
  }
  if (st <= RANK_LO && RANK_LO < en) {
    uint32_t a = st;
    for (int i = 0; i < 32; ++i) {
      uint32_t nx = a + h32[i];
      if (RANK_LO < nx) { result.y = base + i; result.w = (int)(RANK_LO - a); break; }
      a = nx;
    }
  }
  __syncthreads();
  if (tid == 0) bins4[f] = result;
}

// ---------------------------------------------------------------------------
// 3) gather critical-bucket values — 16 px/thread, 4 hoisted float4 loads
// ---------------------------------------------------------------------------
__global__ void gather_kernel(const float* __restrict__ blur,
                              const int4* __restrict__ bins4,
                              float* __restrict__ band,
                              uint32_t* __restrict__ bandcnt) {
  const int T = NPIX / 16;   // 1,048,576 threads
  int t = blockIdx.x * blockDim.x + threadIdx.x;
  float4 v[4];
#pragma unroll
  for (int k = 0; k < 4; ++k) {
    v[k] = *(const float4*)(blur + (size_t)(t + k * T) * 4);
  }
#pragma unroll
  for (int k = 0; k < 4; ++k) {
    int p0 = (t + k * T) * 4;
    int f = frag_of(p0 >> 12, p0 & (WW - 1));
    int4 info = bins4[f];
    float vv[4] = {v[k].x, v[k].y, v[k].z, v[k].w};
#pragma unroll
    for (int e = 0; e < 4; ++e) {
      int b = bin_of(vv[e]);
      if (b == info.x || b == info.y) {
        uint32_t pos = atomicAdd(&bandcnt[f], 1u);
        if (pos < CAP) band[(size_t)f * CAP + pos] = vv[e];
      }
    }
  }
}

// ---------------------------------------------------------------------------
// 4) exact order-statistic selection within the critical buckets
// ---------------------------------------------------------------------------
__global__ void select_kernel(const float* __restrict__ band,
                              const uint32_t* __restrict__ bandcnt,
                              const int4* __restrict__ bins4,
                              float2* __restrict__ vhl) {
  __shared__ float wv[CAP];
  __shared__ float res[2];
  int f = blockIdx.x;
  int tid = threadIdx.x;
  int n = (int)bandcnt[f];
  if (n > CAP) n = CAP;
  for (int i = tid; i < n; i += 256) wv[i] = band[(size_t)f * CAP + i];
  __syncthreads();
  int4 info = bins4[f];
#pragma unroll
  for (int sel = 0; sel < 2; ++sel) {
    int tb = sel ? info.y : info.x;
    int k  = sel ? info.w : info.z;
    for (int i = tid; i < n; i += 256) {
      float w = wv[i];
      if (bin_of(w) != tb) continue;
      int less = 0, leq = 0;
      for (int j = 0; j < n; ++j) {
        float u = wv[j];
        if (bin_of(u) == tb) {
          less += (u < w) ? 1 : 0;
          leq  += (u <= w) ? 1 : 0;
        }
      }
      if (less <= k && k < leq) res[sel] = w;   // unique value; benign race
    }
  }
  __syncthreads();
  if (tid == 0) vhl[f] = make_float2(res[0], res[1]);
}

// ---------------------------------------------------------------------------
// 5) threshold walk — branchless predicated steps (16 per exit check).
//    Each conditional step is EXACTLY the reference's while-iteration:
//    taken  -> th = __fadd_rn(th, ±step) ; not-taken -> no-op.
// ---------------------------------------------------------------------------
__global__ void walk_kernel(const float2* __restrict__ vhl, float* __restrict__ th_out) {
  int lane = threadIdx.x;
  float2 mine = vhl[lane];   // lane f holds fragment f's (V_HI, V_LO)
  float th = 0.5f;           // TH1_INIT
  for (int f = 0; f < NFRAG; ++f) {
    float VH = __shfl(mine.x, f);
    float VL = __shfl(mine.y, f);
    // phase 0: while th >= VH: th -= 0.0005
    while (th >= VH) {
#pragma unroll
      for (int i = 0; i < 16; ++i) {
        float t2 = __fadd_rn(th, -0.0005f);
        th = (th >= VH) ? t2 : th;
      }
    }
    // phase 1: while th < VL: th += 0.0005
    while (th < VL) {
#pragma unroll
      for (int i = 0; i < 16; ++i) {
        float t2 = __fadd_rn(th, 0.0005f);
        th = (th < VL) ? t2 : th;
      }
    }
    if (lane == 0) th_out[f] = th;
  }
}

// ---------------------------------------------------------------------------
// 6) mask + bit-pack — 16 px/thread, 4 hoisted float4 loads, ballot interleave
// ---------------------------------------------------------------------------
__global__ void mask_pack_kernel(const float* __restrict__ blur,
                                 const float* __restrict__ th,
                                 u64* __restrict__ pk) {
  const int T = NPIX / 16;   // 1,048,576 threads
  int t = blockIdx.x * blockDim.x + threadIdx.x;
  float4 v[4];
#pragma unroll
  for (int k = 0; k < 4; ++k) {
    v[k] = *(const float4*)(blur + (size_t)(t + k * T) * 4);
  }
  int lane = threadIdx.x & 63;
#pragma unroll
  for (int k = 0; k < 4; ++k) {
    int g = t + k * T;           // 4-px group index
    int p0 = g * 4;
    float tf = th[frag_of(p0 >> 12, p0 & (WW - 1))];
    u64 b0 = __ballot(v[k].x > tf);
    u64 b1 = __ballot(v[k].y > tf);
    u64 b2 = __ballot(v[k].z > tf);
    u64 b3 = __ballot(v[k].w > tf);
    if ((lane & 15) == 0) {
      int sh = lane;             // 0,16,32,48
      u64 w = spread4(b0 >> sh) | (spread4(b1 >> sh) << 1)
            | (spread4(b2 >> sh) << 2) | (spread4(b3 >> sh) << 3);
      int base_word = ((g - lane) * 4) >> 6;
      pk[base_word + (lane >> 4)] = w;
    }
  }
}

// ---------------------------------------------------------------------------
// 7) fused dilate (H+V) on packed bits; OOB = 0 (clipped window).
// ---------------------------------------------------------------------------
__global__ void dilate_kernel(const u64* __restrict__ in, u64* __restrict__ out) {
  __shared__ u64 hm[68][16];
  int bx = blockIdx.x & 3;
  int by = blockIdx.x >> 2;
  int r0 = by * 64, c0 = bx * 16;
  int tid = threadIdx.x;
  for (int it = tid; it < 68 * 16; it += 256) {
    int rr = it >> 4;
    int cc = it & 15;
    int gy = r0 - 2 + rr;
    int gx = c0 + cc;
    u64 m = 0, l = 0, r = 0;
    if ((unsigned)gy < (unsigned)HH) {
      m = in[gy * WPR + gx];
      l = (gx > 0) ? in[gy * WPR + gx - 1] : 0ull;
      r = (gx < WPR - 1) ? in[gy * WPR + gx + 1] : 0ull;
    }
    hm[rr][cc] = m | (m << 1) | (m << 2) | (m >> 1) | (m >> 2)
                   | (l >> 62) | (l >> 63) | (r << 62) | (r << 63);
  }
  __syncthreads();
  for (int it = tid; it < 64 * 16; it += 256) {
    int rr = it >> 4;
    int cc = it & 15;
    u64 v = hm[rr][cc] | hm[rr + 1][cc] | hm[rr + 2][cc] | hm[rr + 3][cc] | hm[rr + 4][cc];
    out[(r0 + rr) * WPR + c0 + cc] = v;
  }
}

// ---------------------------------------------------------------------------
// 8) fused erode (De Morgan) + unpack to f32: out = 1 - bit(dilate(~d1)).
// ---------------------------------------------------------------------------
__global__ void erode_unpack_kernel(const u64* __restrict__ in, float* __restrict__ out) {
  __shared__ u64 hm[68][16];
  __shared__ u64 d2[64][16];
  int bx = blockIdx.x & 3;
  int by = blockIdx.x >> 2;
  int r0 = by * 64, c0 = bx * 16;
  int tid = threadIdx.x;
  for (int it = tid; it < 68 * 16; it += 256) {
    int rr = it >> 4;
    int cc = it & 15;
    int gy = r0 - 2 + rr;
    int gx = c0 + cc;
    u64 m = 0, l = 0, r = 0;
    if ((unsigned)gy < (unsigned)HH) {
      m = ~in[gy * WPR + gx];
      l = (gx > 0) ? ~in[gy * WPR + gx - 1] : 0ull;
      r = (gx < WPR - 1) ? ~in[gy * WPR + gx + 1] : 0ull;
    }
    hm[rr][cc] = m | (m << 1) | (m << 2) | (m >> 1) | (m >> 2)
                   | (l >> 62) | (l >> 63) | (r << 62) | (r << 63);
  }
  __syncthreads();
  for (int it = tid; it < 64 * 16; it += 256) {
    int rr = it >> 4;
    int cc = it & 15;
    d2[rr][cc] = hm[rr][cc] | hm[rr + 1][cc] | hm[rr + 2][cc] | hm[rr + 3][cc] | hm[rr + 4][cc];
  }
  __syncthreads();
  int colbase = c0 * 64;
  for (int it = tid; it < 64 * 256; it += 256) {
    int rr = it >> 8;
    int px0 = (it & 255) * 4;
    u64 w = d2[rr][px0 >> 6];
    int sh = px0 & 63;
    float4 o;
    o.x = (float)(1 - (int)((w >> (sh + 0)) & 1ull));
    o.y = (float)(1 - (int)((w >> (sh + 1)) & 1ull));
    o.z = (float)(1 - (int)((w >> (sh + 2)) & 1ull));
    o.w = (float)(1 - (int)((w >> (sh + 3)) & 1ull));
    *(float4*)(out + (size_t)(r0 + rr) * WW + colbase + px0) = o;
  }
}

// ---------------------------------------------------------------------------
extern "C" void kernel_launch(void* const* d_in, const int* in_sizes, int n_in,
                              void* d_out, int out_size, void* d_ws, size_t ws_size,
                              hipStream_t stream) {
  const float* x = (const float*)d_in[0];
  if (n_in > 1 && in_sizes[0] != NPIX) x = (const float*)d_in[1];
  float* out = (float*)d_out;
  char* ws = (char*)d_ws;

  // workspace layout — TOTAL ~7.4 MB
  const size_t OFF_HIST = 0;          // 2,097,152
  const size_t OFF_TH   = 2097152;    // 256
  const size_t OFF_PKA  = 2097408;    // 2,097,152
  const size_t OFF_PKB  = 4194560;    // 2,097,152
  const size_t OFF_BCNT = 6291712;    // 256
  const size_t OFF_BINS = 6291968;    // 1,024
  const size_t OFF_VHL  = 6292992;    // 512
  const size_t OFF_BAND = 6293504;    // 1,048,576 (end ~7.34 MB)
  uint32_t* hist    = (uint32_t*)(ws + OFF_HIST);
  float*    th      = (float*)(ws + OFF_TH);
  u64*      PKA     = (u64*)(ws + OFF_PKA);
  u64*      PKB     = (u64*)(ws + OFF_PKB);
  uint32_t* bandcnt = (uint32_t*)(ws + OFF_BCNT);
  int4*     bins4   = (int4*)(ws + OFF_BINS);
  float2*   vhl     = (float2*)(ws + OFF_VHL);
  float*    band    = (float*)(ws + OFF_BAND);

  float* blurred = out;   // blur lives in d_out; erode_unpack rewrites it

  const int TPB = 256;
  const int NB16 = NPIX / 16 / TPB;   // 4096 blocks (16 px/thread kernels)

  hipMemsetAsync(hist, 0, (size_t)NFRAG * NBINS * sizeof(uint32_t), stream);
  hipMemsetAsync(bandcnt, 0, NFRAG * sizeof(uint32_t), stream);
  blur_hist_kernel<<<1024, TPB, 0, stream>>>(x, blurred, hist);
  findcrit_kernel<<<NFRAG, TPB, 0, stream>>>(hist, bins4);
  gather_kernel<<<NB16, TPB, 0, stream>>>(blurred, bins4, band, bandcnt);
  select_kernel<<<NFRAG, TPB, 0, stream>>>(band, bandcnt, bins4, vhl);
  walk_kernel<<<1, 64, 0, stream>>>(vhl, th);
  mask_pack_kernel<<<NB16, TPB, 0, stream>>>(blurred, th, PKA);
  dilate_kernel<<<256, TPB, 0, stream>>>(PKA, PKB);
  erode_unpack_kernel<<<256, TPB, 0, stream>>>(PKB, out);
}